// Round 2
// baseline (86.530 us; speedup 1.0000x reference)
//
#include <hip/hip_runtime.h>

// Problem constants
#define NP 256     // particles per (bs, h) slice: (2564-4)/10
#define OD 10      // OBS_DIM
#define ROWLEN 2564
#define NB 512     // bs*horizon = 16*32
#define FINF 3.4e38f

// One block per (bs*h) slice b in [0,512), one thread per particle t in [0,256).
// ws layout: ws[0..511]    = per-block chamfer sums of (3*d1 + d2)
//            ws[512..1023] = per-block weighted action L1 (h==1 row ×10)
__global__ __launch_bounds__(256) void cham_main(const float* __restrict__ preds,
                                                 const float* __restrict__ targ,
                                                 float* __restrict__ ws) {
    const int b = blockIdx.x;
    const int t = threadIdx.x;
    const int base = b * ROWLEN;
    const int ob = base + 4;

    // Feature dims 5:9 packed as float4 per particle -> single ds_read_b128
    // wave-uniform broadcast per particle per side in the main loop.
    __shared__ float4 sFA[NP];
    __shared__ float4 sFB[NP];

    const int fo = ob + t * OD + 5;
    const float a0 = preds[fo + 0], a1 = preds[fo + 1],
                a2 = preds[fo + 2], a3 = preds[fo + 3];
    const float p0 = targ[fo + 0], p1 = targ[fo + 1],
                p2 = targ[fo + 2], p3 = targ[fo + 3];
    sFA[t] = make_float4(a0, a1, a2, a3);
    sFB[t] = make_float4(p0, p1, p2, p3);
    __syncthreads();

    // Fused dual argmin over the 256x256 squared-distance matrix P:
    //   id2[t] = argmin_k P[t, k]   (axis=2 argmin: pred row t vs targ k)
    //   id1[t] = argmin_k P[k, t]   (axis=1 argmin: pred k vs targ col t)
    // 4 independent chains (k ≡ u mod 4) for ILP; exact-value + lower-index
    // merge preserves jnp.argmin first-index tie-break.
    float bd2c[4], bd1c[4];
    int   bi2c[4], bi1c[4];
#pragma unroll
    for (int u = 0; u < 4; ++u) {
        bd2c[u] = FINF; bd1c[u] = FINF; bi2c[u] = 0; bi1c[u] = 0;
    }

    for (int k = 0; k < NP; k += 4) {
#pragma unroll
        for (int u = 0; u < 4; ++u) {
            const float4 fb = sFB[k + u];
            const float4 fa = sFA[k + u];
            float dx0 = a0 - fb.x, dx1 = a1 - fb.y,
                  dx2 = a2 - fb.z, dx3 = a3 - fb.w;
            float d2 = fmaf(dx0, dx0, fmaf(dx1, dx1, fmaf(dx2, dx2, dx3 * dx3)));
            float ex0 = fa.x - p0, ex1 = fa.y - p1,
                  ex2 = fa.z - p2, ex3 = fa.w - p3;
            float d1 = fmaf(ex0, ex0, fmaf(ex1, ex1, fmaf(ex2, ex2, ex3 * ex3)));
            const bool c2 = d2 < bd2c[u];
            bd2c[u] = c2 ? d2 : bd2c[u];
            bi2c[u] = c2 ? (k + u) : bi2c[u];
            const bool c1 = d1 < bd1c[u];
            bd1c[u] = c1 ? d1 : bd1c[u];
            bi1c[u] = c1 ? (k + u) : bi1c[u];
        }
    }

    float bd2 = bd2c[0]; int id2 = bi2c[0];
    float bd1 = bd1c[0]; int id1 = bi1c[0];
#pragma unroll
    for (int u = 1; u < 4; ++u) {
        bool m2 = (bd2c[u] < bd2) || (bd2c[u] == bd2 && bi2c[u] < id2);
        bd2 = m2 ? bd2c[u] : bd2;  id2 = m2 ? bi2c[u] : id2;
        bool m1 = (bd1c[u] < bd1) || (bd1c[u] == bd1 && bi1c[u] < id1);
        bd1 = m1 ? bd1c[u] : bd1;  id1 = m1 ? bi1c[u] : id1;
    }

    // Chamfer L1 terms over all 10 obs dims.
    //   particle_dist1[b, t] = sum_d |obs[b, id1[t], d] - obs_targ[b, t, d]|
    //   particle_dist2[b, t] = sum_d |obs_targ[b, id2[t], d] - obs[b, t, d]|
    float s1 = 0.f, s2 = 0.f;
#pragma unroll
    for (int d = 0; d < OD; ++d) {
        float o_t   = preds[ob + t * OD + d];
        float ot_t  = targ [ob + t * OD + d];
        float o_i1  = preds[ob + id1 * OD + d];
        float ot_i2 = targ [ob + id2 * OD + d];
        s1 += fabsf(o_i1 - ot_t);
        s2 += fabsf(ot_i2 - o_t);
    }
    float v = 3.0f * s1 + s2;

    // Block reduce: wave64 shuffle then cross-wave via LDS.
#pragma unroll
    for (int off = 32; off > 0; off >>= 1) v += __shfl_down(v, off, 64);

    __shared__ float wsum[4];
    if ((t & 63) == 0) wsum[t >> 6] = v;
    __syncthreads();
    if (t == 0) {
        ws[b] = wsum[0] + wsum[1] + wsum[2] + wsum[3];
        // action L1 for this (bs, h): first 4 channels.
        float l1 = 0.f;
#pragma unroll
        for (int d = 0; d < 4; ++d) l1 += fabsf(preds[base + d] - targ[base + d]);
        l1 *= 0.25f;
        const int h = b & 31;
        ws[NB + b] = (h == 1) ? l1 * 10.0f : l1;
    }
}

__global__ __launch_bounds__(512) void cham_final(const float* __restrict__ ws,
                                                  float* __restrict__ out) {
    const int t = threadIdx.x;
    float cham = ws[t];
    float act  = ws[NB + t];
    // a0_loss uses the UNWEIGHTED h==1 values; weighted stored, so ×0.1.
    float a0 = ((t & 31) == 1) ? act * 0.1f : 0.f;

#pragma unroll
    for (int off = 32; off > 0; off >>= 1) {
        cham += __shfl_down(cham, off, 64);
        act  += __shfl_down(act,  off, 64);
        a0   += __shfl_down(a0,   off, 64);
    }
    __shared__ float sc[8], sa[8], s0[8];
    if ((t & 63) == 0) { int w = t >> 6; sc[w] = cham; sa[w] = act; s0[w] = a0; }
    __syncthreads();
    if (t == 0) {
        float C = 0.f, A = 0.f, Z = 0.f;
#pragma unroll
        for (int w = 0; w < 8; ++w) { C += sc[w]; A += sa[w]; Z += s0[w]; }
        // chamfer.mean() = sum(3*d1+d2) / (TARGET_WEIGHT+1) / (512*256*10)
        const float cham_mean = C * (1.0f / (4.0f * (float)NB * (float)NP * (float)OD));
        out[0] = A * (1.0f / (float)NB) + cham_mean;  // loss
        out[1] = Z * (1.0f / 16.0f);                  // a0_loss
    }
}

extern "C" void kernel_launch(void* const* d_in, const int* in_sizes, int n_in,
                              void* d_out, int out_size, void* d_ws, size_t ws_size,
                              hipStream_t stream) {
    const float* preds = (const float*)d_in[0];
    const float* targ  = (const float*)d_in[1];
    float* ws  = (float*)d_ws;
    float* out = (float*)d_out;

    cham_main <<<NB, 256, 0, stream>>>(preds, targ, ws);
    cham_final<<<1, 512, 0, stream>>>(ws, out);
}